// Round 1
// baseline (218.845 us; speedup 1.0000x reference)
//
#include <hip/hip_runtime.h>

// Y = (Bm@A) @ a_term + (Bm@C) @ c_term as one bf16 MFMA GEMM.
// R5: occupancy + pipelining. LDS cut 50176->36864 B/block (Z aliased into the
// consumed J staging slots; per-wave in-order DS makes this safe) -> 4 blocks/CU
// guaranteed by __launch_bounds__(256,4). Grid 1024 persistent blocks, 4 tiles
// each, with register-double-buffered global prefetch of tile t+1 during tile t.
// A-fragments reloaded per tile AFTER phase1 (LICM defeated via opaque asm) so
// peak VGPR stays <=128. Phase-1 LDS reads software-pipelined depth 2.
// Per-wave LDS (dwords): [0..1535] J stage / Z rows / epilogue, [1536..2303] X stage.
// Z row (pi,i) at dword pi*396 + i*68 (stagger keeps old bank-group profile).

typedef __bf16 bf16x8 __attribute__((ext_vector_type(8)));
typedef float floatx4 __attribute__((ext_vector_type(4)));

#define RSW 68  // Z row stride in dwords

__global__ __launch_bounds__(256) void prep_kernel(const float* __restrict__ A,
                                                   const float* __restrict__ Bm,
                                                   const float* __restrict__ C,
                                                   __bf16* __restrict__ acat) {
    int tid = blockIdx.x * 256 + threadIdx.x;  // 0..4095
    int f = tid >> 6;
    int e = tid & 63;
    float m = 0.f, m2 = 0.f;
    #pragma unroll 8
    for (int k = 0; k < 64; ++k) {
        float b = Bm[f * 64 + k];
        m  = fmaf(b, A[k * 64 + e], m);
        m2 = fmaf(b, C[k * 64 + e], m2);
    }
    acat[f * 128 + 2 * e]     = (__bf16)m;   // k = 2e   : M[f,e]
    acat[f * 128 + 2 * e + 1] = (__bf16)m2;  // k = 2e+1 : M2[f,e]
}

static __device__ __forceinline__ unsigned pk(float a, float c) {
    unsigned short ua = __builtin_bit_cast(unsigned short, (__bf16)a);
    unsigned short uc = __builtin_bit_cast(unsigned short, (__bf16)c);
    return ((unsigned)uc << 16) | ua;
}

__global__ __launch_bounds__(256, 4) void main_kernel(const float* __restrict__ X,
                                                      const float* __restrict__ J,
                                                      const __bf16* __restrict__ acat,
                                                      float* __restrict__ out) {
    __shared__ __align__(16) float buf[4][2304];  // 36,864 B -> 4 blocks/CU

    const int wave = threadIdx.x >> 6;
    const int lane = threadIdx.x & 63;
    const int l15  = lane & 15;
    const int quad = lane >> 4;
    const int pb0  = blockIdx.x * 64 + wave * 4;  // tile t: pbase = pb0 + t*16

    float* stg = buf[wave];

    // ---- prologue: prefetch tile 0 into registers ----
    floatx4 jt[6], xt[3];
    {
        const floatx4* jg = (const floatx4*)(J + (size_t)pb0 * 384);
        const floatx4* xg = (const floatx4*)(X + (size_t)pb0 * 192);
        #pragma unroll
        for (int u = 0; u < 6; ++u) jt[u] = jg[u * 64 + lane];
        #pragma unroll
        for (int u = 0; u < 3; ++u) xt[u] = xg[u * 64 + lane];
    }

    #pragma unroll
    for (int t = 0; t < 4; ++t) {
        const int pbase = pb0 + t * 16;

        // ---- stage current tile regs -> LDS (coalesced, every line once) ----
        {
            floatx4* sj = (floatx4*)stg;
            floatx4* sx = (floatx4*)(stg + 1536);
            #pragma unroll
            for (int u = 0; u < 6; ++u) sj[u * 64 + lane] = jt[u];
            #pragma unroll
            for (int u = 0; u < 3; ++u) sx[u * 64 + lane] = xt[u];
        }

        // ---- prefetch tile t+1 (latency hides under phase 1 + mfma) ----
        if (t < 3) {
            const floatx4* jg = (const floatx4*)(J + (size_t)(pbase + 16) * 384);
            const floatx4* xg = (const floatx4*)(X + (size_t)(pbase + 16) * 192);
            #pragma unroll
            for (int u = 0; u < 6; ++u) jt[u] = jg[u * 64 + lane];
            #pragma unroll
            for (int u = 0; u < 3; ++u) xt[u] = xg[u * 64 + lane];
        }

        __asm__ volatile("s_waitcnt lgkmcnt(0)" ::: "memory");

        // ---- phase 1: geometry, lane = d; Z rows written INTO J slot pi ----
        // software-pipelined depth 2 (aliasing stops the compiler doing it)
        float2 ja, jb, jc; float xx, xy, xz;
        {
            const float* jst = stg + lane * 6;
            ja = *(const float2*)(jst);
            jb = *(const float2*)(jst + 2);
            jc = *(const float2*)(jst + 4);
            const float* xst = stg + 1536 + lane * 3;
            xx = xst[0]; xy = xst[1]; xz = xst[2];
        }
        #pragma unroll
        for (int pi = 0; pi < 4; ++pi) {
            float2 na = ja, nb = jb, nc = jc; float nx = xx, ny = xy, nz = xz;
            if (pi < 3) {
                const float* jst = stg + (pi + 1) * 384 + lane * 6;
                na = *(const float2*)(jst);
                nb = *(const float2*)(jst + 2);
                nc = *(const float2*)(jst + 4);
                const float* xst = stg + 1536 + (pi + 1) * 192 + lane * 3;
                nx = xst[0]; ny = xst[1]; nz = xst[2];
            }

            float a0x = ja.x, a0y = jb.x, a0z = jc.x;  // J col 0
            float a1x = ja.y, a1y = jb.y, a1z = jc.y;  // J col 1

            float n0 = sqrtf(a0x * a0x + a0y * a0y + a0z * a0z);
            float r0 = 1.0f / fmaxf(n0, 1e-12f);
            float b1x = a0x * r0, b1y = a0y * r0, b1z = a0z * r0;

            float d  = b1x * a1x + b1y * a1y + b1z * a1z;
            float ux = a1x - d * b1x, uy = a1y - d * b1y, uz = a1z - d * b1z;
            float n2 = sqrtf(ux * ux + uy * uy + uz * uz);
            float r2 = 1.0f / fmaxf(n2, 1e-12f);
            float b2x = ux * r2, b2y = uy * r2, b2z = uz * r2;

            float b3x = b1y * b2z - b1z * b2y;
            float b3y = b1z * b2x - b1x * b2z;
            float b3z = b1x * b2y - b1y * b2x;

            float rt0 = b1x * xx + b1y * xy + b1z * xz;
            float rt1 = b2x * xx + b2y * xy + b2z * xz;
            float rt2 = b3x * xx + b3y * xy + b3z * xz;

            float s = rt1 - rt2, tt = rt1 + rt2;

            unsigned* zr = (unsigned*)(stg + pi * 396);  // inside J slot pi
            zr[lane]           = pk(b2x * s + b3x * tt, b1x * rt0);
            zr[RSW + lane]     = pk(b2y * s + b3y * tt, b1y * rt0);
            zr[2 * RSW + lane] = pk(b2z * s + b3z * tt, b1z * rt0);

            ja = na; jb = nb; jc = nc; xx = nx; xy = ny; xz = nz;
        }

        __asm__ volatile("s_waitcnt lgkmcnt(0)" ::: "memory");

        // ---- A-fragments: reload per tile (L2-hot 16 KB), AFTER phase1 so the
        //      64 VGPRs are dead during geometry; opaque asm defeats LICM ----
        const __bf16* ap = acat;
        __asm__ volatile("" : "+s"(ap));
        bf16x8 afrag[4][4];
        #pragma unroll
        for (int mt = 0; mt < 4; ++mt)
            #pragma unroll
            for (int kc = 0; kc < 4; ++kc)
                afrag[mt][kc] = *(const bf16x8*)(ap + (mt * 16 + l15) * 128 + kc * 32 + quad * 8);

        // ---- phase 2: 16x mfma 16x16x32, K=128, rows 0..11 valid ----
        floatx4 acc[4];
        #pragma unroll
        for (int mt = 0; mt < 4; ++mt) acc[mt] = (floatx4){0.f, 0.f, 0.f, 0.f};

        int row = l15 > 11 ? 11 : l15;  // clamp: n>=12 columns are garbage, never stored
        int pz  = (row * 21846) >> 16;  // row / 3
        int iz  = row - pz * 3;
        const __bf16* zb = (const __bf16*)stg + pz * 792 + iz * 136;
        #pragma unroll
        for (int kc = 0; kc < 4; ++kc) {
            bf16x8 b = *(const bf16x8*)(zb + kc * 32 + quad * 8);
            #pragma unroll
            for (int mt = 0; mt < 4; ++mt)
                acc[mt] = __builtin_amdgcn_mfma_f32_16x16x32_bf16(afrag[mt][kc], b, acc[mt], 0, 0, 0);
        }

        __asm__ volatile("s_waitcnt lgkmcnt(0)" ::: "memory");

        // ---- epilogue: D[f][n] -> LDS [p_local*196 + f*3 + i] (reuse J region) ----
        float* dl = stg;
        #pragma unroll
        for (int mt = 0; mt < 4; ++mt) {
            int n = l15;
            if (n < 12) {
                int pl = (n * 21846) >> 16;  // n / 3
                int i  = n - pl * 3;
                float* dst = dl + pl * 196 + i;
                #pragma unroll
                for (int r = 0; r < 4; ++r) {
                    int f = mt * 16 + quad * 4 + r;
                    dst[f * 3] = acc[mt][r];
                }
            }
        }

        __asm__ volatile("s_waitcnt lgkmcnt(0)" ::: "memory");

        // ---- coalesced store: 4 points x 48 float4 = 192 float4 ----
        floatx4* og = (floatx4*)(out + (size_t)pbase * 192);
        #pragma unroll
        for (int u = 0; u < 3; ++u) {
            int g  = u * 64 + lane;
            int pg = (g * 1366) >> 16;  // g / 48
            int o  = g - pg * 48;
            og[g] = *(const floatx4*)(dl + pg * 196 + o * 4);
        }
    }
}

extern "C" void kernel_launch(void* const* d_in, const int* in_sizes, int n_in,
                              void* d_out, int out_size, void* d_ws, size_t ws_size,
                              hipStream_t stream) {
    const float* X  = (const float*)d_in[0];
    const float* J  = (const float*)d_in[1];
    const float* A  = (const float*)d_in[2];
    const float* Bm = (const float*)d_in[3];
    const float* C  = (const float*)d_in[4];
    float* out = (float*)d_out;
    __bf16* acat = (__bf16*)d_ws;  // 64x128 bf16 = 16 KB

    prep_kernel<<<16, 256, 0, stream>>>(A, Bm, C, acat);

    // 65536 points = 1024 persistent blocks x 4 waves x 4 points x 4 tiles
    main_kernel<<<1024, 256, 0, stream>>>(X, J, acat, out);
}

// Round 2
// 211.216 us; speedup vs baseline: 1.0361x; 1.0361x over previous
//
#include <hip/hip_runtime.h>

// Y = (Bm@A) @ a_term + (Bm@C) @ c_term as one bf16 MFMA GEMM.
// R6: R4 structure (grid 4096, one 4-point tile per wave, afrag loaded once)
// + R5's LDS cut: Z rows aliased into the already-consumed J staging slots.
// Per-wave LDS drops 3120 -> 2304 dwords; block 36,864 B -> 4 blocks/CU
// (launch_bounds(256,4)) = 16 waves/CU vs R4's 12. Phase-1 LDS reads are
// explicitly software-pipelined depth 2 (the Z/J aliasing stops the compiler
// hoisting slot pi+1 reads above slot pi Z-writes on its own).
// Per-wave LDS (dwords): [0..1535] J stage / Z rows / epilogue, [1536..2303] X stage.
// Z row (pi,i) at dword pi*396 + i*68.

typedef __bf16 bf16x8 __attribute__((ext_vector_type(8)));
typedef float floatx4 __attribute__((ext_vector_type(4)));

#define RSW 68  // Z row stride in dwords

__global__ __launch_bounds__(64) void prep_kernel(const float* __restrict__ A,
                                                  const float* __restrict__ Bm,
                                                  const float* __restrict__ C,
                                                  __bf16* __restrict__ acat) {
    int tid = blockIdx.x * 64 + threadIdx.x;  // 0..4095, one wave per block
    int f = tid >> 6;
    int e = tid & 63;
    float m = 0.f, m2 = 0.f;
    #pragma unroll 8
    for (int k = 0; k < 64; ++k) {
        float b = Bm[f * 64 + k];
        m  = fmaf(b, A[k * 64 + e], m);
        m2 = fmaf(b, C[k * 64 + e], m2);
    }
    acat[f * 128 + 2 * e]     = (__bf16)m;   // k = 2e   : M[f,e]
    acat[f * 128 + 2 * e + 1] = (__bf16)m2;  // k = 2e+1 : M2[f,e]
}

static __device__ __forceinline__ unsigned pk(float a, float c) {
    unsigned short ua = __builtin_bit_cast(unsigned short, (__bf16)a);
    unsigned short uc = __builtin_bit_cast(unsigned short, (__bf16)c);
    return ((unsigned)uc << 16) | ua;
}

__global__ __launch_bounds__(256, 4) void main_kernel(const float* __restrict__ X,
                                                      const float* __restrict__ J,
                                                      const __bf16* __restrict__ acat,
                                                      float* __restrict__ out) {
    __shared__ __align__(16) float buf[4][2304];  // 36,864 B -> 4 blocks/CU

    const int wave = threadIdx.x >> 6;
    const int lane = threadIdx.x & 63;
    const int l15  = lane & 15;
    const int quad = lane >> 4;
    const int pbase = blockIdx.x * 16 + wave * 4;  // 4 points per wave

    float* stg = buf[wave];

    // ---- stage J (384 f4) and X (192 f4) coalesced: every line touched once ----
    {
        const floatx4* jg = (const floatx4*)(J + (size_t)pbase * 384);
        const floatx4* xg = (const floatx4*)(X + (size_t)pbase * 192);
        floatx4 jt[6], xt[3];
        #pragma unroll
        for (int t = 0; t < 6; ++t) jt[t] = jg[t * 64 + lane];
        #pragma unroll
        for (int t = 0; t < 3; ++t) xt[t] = xg[t * 64 + lane];
        floatx4* sj = (floatx4*)stg;
        floatx4* sx = (floatx4*)(stg + 1536);
        #pragma unroll
        for (int t = 0; t < 6; ++t) sj[t * 64 + lane] = jt[t];
        #pragma unroll
        for (int t = 0; t < 3; ++t) sx[t * 64 + lane] = xt[t];
    }

    __asm__ volatile("s_waitcnt lgkmcnt(0)" ::: "memory");

    // ---- phase 1: geometry, lane = d; Z rows written INTO J slot pi ----
    // software-pipelined depth 2 (aliasing stops the compiler doing it)
    float2 ja, jb, jc; float xx, xy, xz;
    {
        const float* jst = stg + lane * 6;
        ja = *(const float2*)(jst);
        jb = *(const float2*)(jst + 2);
        jc = *(const float2*)(jst + 4);
        const float* xst = stg + 1536 + lane * 3;
        xx = xst[0]; xy = xst[1]; xz = xst[2];
    }
    #pragma unroll
    for (int pi = 0; pi < 4; ++pi) {
        float2 na = ja, nb = jb, nc = jc; float nx = xx, ny = xy, nz = xz;
        if (pi < 3) {
            const float* jst = stg + (pi + 1) * 384 + lane * 6;
            na = *(const float2*)(jst);
            nb = *(const float2*)(jst + 2);
            nc = *(const float2*)(jst + 4);
            const float* xst = stg + 1536 + (pi + 1) * 192 + lane * 3;
            nx = xst[0]; ny = xst[1]; nz = xst[2];
        }

        float a0x = ja.x, a0y = jb.x, a0z = jc.x;  // J col 0
        float a1x = ja.y, a1y = jb.y, a1z = jc.y;  // J col 1

        float n0 = sqrtf(a0x * a0x + a0y * a0y + a0z * a0z);
        float r0 = 1.0f / fmaxf(n0, 1e-12f);
        float b1x = a0x * r0, b1y = a0y * r0, b1z = a0z * r0;

        float d  = b1x * a1x + b1y * a1y + b1z * a1z;
        float ux = a1x - d * b1x, uy = a1y - d * b1y, uz = a1z - d * b1z;
        float n2 = sqrtf(ux * ux + uy * uy + uz * uz);
        float r2 = 1.0f / fmaxf(n2, 1e-12f);
        float b2x = ux * r2, b2y = uy * r2, b2z = uz * r2;

        float b3x = b1y * b2z - b1z * b2y;
        float b3y = b1z * b2x - b1x * b2z;
        float b3z = b1x * b2y - b1y * b2x;

        float rt0 = b1x * xx + b1y * xy + b1z * xz;
        float rt1 = b2x * xx + b2y * xy + b2z * xz;
        float rt2 = b3x * xx + b3y * xy + b3z * xz;

        float s = rt1 - rt2, tt = rt1 + rt2;

        unsigned* zr = (unsigned*)(stg + pi * 396);  // inside consumed J slot pi
        zr[lane]           = pk(b2x * s + b3x * tt, b1x * rt0);
        zr[RSW + lane]     = pk(b2y * s + b3y * tt, b1y * rt0);
        zr[2 * RSW + lane] = pk(b2z * s + b3z * tt, b1z * rt0);

        ja = na; jb = nb; jc = nc; xx = nx; xy = ny; xz = nz;
    }

    // ---- A-fragments (L2-resident 16 KB table), loaded once, after phase 1 ----
    bf16x8 afrag[4][4];
    #pragma unroll
    for (int mt = 0; mt < 4; ++mt)
        #pragma unroll
        for (int kc = 0; kc < 4; ++kc)
            afrag[mt][kc] = *(const bf16x8*)(acat + (mt * 16 + l15) * 128 + kc * 32 + quad * 8);

    __asm__ volatile("s_waitcnt lgkmcnt(0)" ::: "memory");

    // ---- phase 2: 16x mfma 16x16x32, K=128, rows 0..11 valid ----
    floatx4 acc[4];
    #pragma unroll
    for (int mt = 0; mt < 4; ++mt) acc[mt] = (floatx4){0.f, 0.f, 0.f, 0.f};

    int row = l15 > 11 ? 11 : l15;  // clamp: n>=12 columns are garbage, never stored
    int pz  = (row * 21846) >> 16;  // row / 3
    int iz  = row - pz * 3;
    const __bf16* zb = (const __bf16*)stg + pz * 792 + iz * 136;
    #pragma unroll
    for (int kc = 0; kc < 4; ++kc) {
        bf16x8 b = *(const bf16x8*)(zb + kc * 32 + quad * 8);
        #pragma unroll
        for (int mt = 0; mt < 4; ++mt)
            acc[mt] = __builtin_amdgcn_mfma_f32_16x16x32_bf16(afrag[mt][kc], b, acc[mt], 0, 0, 0);
    }

    __asm__ volatile("s_waitcnt lgkmcnt(0)" ::: "memory");

    // ---- epilogue: D[f][n] -> LDS [p_local*196 + f*3 + i] (reuse J region) ----
    float* dl = stg;
    #pragma unroll
    for (int mt = 0; mt < 4; ++mt) {
        int n = l15;
        if (n < 12) {
            int pl = (n * 21846) >> 16;  // n / 3
            int i  = n - pl * 3;
            float* dst = dl + pl * 196 + i;
            #pragma unroll
            for (int r = 0; r < 4; ++r) {
                int f = mt * 16 + quad * 4 + r;
                dst[f * 3] = acc[mt][r];
            }
        }
    }

    __asm__ volatile("s_waitcnt lgkmcnt(0)" ::: "memory");

    // ---- coalesced store: 4 points x 48 float4 = 192 float4 ----
    floatx4* og = (floatx4*)(out + (size_t)pbase * 192);
    #pragma unroll
    for (int t = 0; t < 3; ++t) {
        int g  = t * 64 + lane;
        int pg = (g * 1366) >> 16;  // g / 48
        int o  = g - pg * 48;
        og[g] = *(const floatx4*)(dl + pg * 196 + o * 4);
    }
}

extern "C" void kernel_launch(void* const* d_in, const int* in_sizes, int n_in,
                              void* d_out, int out_size, void* d_ws, size_t ws_size,
                              hipStream_t stream) {
    const float* X  = (const float*)d_in[0];
    const float* J  = (const float*)d_in[1];
    const float* A  = (const float*)d_in[2];
    const float* Bm = (const float*)d_in[3];
    const float* C  = (const float*)d_in[4];
    float* out = (float*)d_out;
    __bf16* acat = (__bf16*)d_ws;  // 64x128 bf16 = 16 KB

    prep_kernel<<<64, 64, 0, stream>>>(A, Bm, C, acat);

    // 65536 points = 4096 blocks x 4 waves x 4 points
    main_kernel<<<4096, 256, 0, stream>>>(X, J, acat, out);
}

// Round 3
// 204.810 us; speedup vs baseline: 1.0685x; 1.0313x over previous
//
#include <hip/hip_runtime.h>

// Y = (Bm@A) @ a_term + (Bm@C) @ c_term as one bf16 MFMA GEMM.
// R7: kill the per-CU vector-memory-path saturation (measured 10.5 B/cyc/CU ==
// the per-CU global-path ceiling). Two changes:
//  1. acat (16 KB, was re-read from L2 by EVERY wave = 268 MB) is staged once
//     per block into LDS (XOR-swizzled, (row&7)<<2 dwords, so fragment reads
//     are 2-way bank-aliased = free). -43% of per-CU global bytes.
//  2. J/X are read per-lane directly into registers (3x dwordx2 / 3x dword),
//     prefetched before the acat stage so HBM latency hides under it. All
//     bytes of every line are used (dense), so HBM traffic is unchanged; this
//     deletes the J/X LDS round-trip, two lgkmcnt drains, and the stride-6
//     phase-1 bank conflicts.
// Per-block LDS (dwords): [0..4095] acat (swizzled), then 4 x 816 per-wave
// Z/epilogue slots. 29,440 B/block -> 4 blocks/CU easily; wave-private slots
// need no barriers (in-order DS + lgkmcnt drains).

typedef __bf16 bf16x8 __attribute__((ext_vector_type(8)));
typedef float floatx4 __attribute__((ext_vector_type(4)));

#define ZRS  68   // Z row stride in dwords
#define WLDS 816  // per-wave LDS dwords (12 Z rows x 68, epilogue aliases)

__global__ __launch_bounds__(64) void prep_kernel(const float* __restrict__ A,
                                                  const float* __restrict__ Bm,
                                                  const float* __restrict__ C,
                                                  __bf16* __restrict__ acat) {
    int tid = blockIdx.x * 64 + threadIdx.x;  // 0..4095, one wave per block
    int f = tid >> 6;
    int e = tid & 63;
    float m = 0.f, m2 = 0.f;
    #pragma unroll 8
    for (int k = 0; k < 64; ++k) {
        float b = Bm[f * 64 + k];
        m  = fmaf(b, A[k * 64 + e], m);
        m2 = fmaf(b, C[k * 64 + e], m2);
    }
    acat[f * 128 + 2 * e]     = (__bf16)m;   // k = 2e   : M[f,e]  (pairs a_term)
    acat[f * 128 + 2 * e + 1] = (__bf16)m2;  // k = 2e+1 : M2[f,e] (pairs c_term)
}

static __device__ __forceinline__ unsigned pk(float a, float c) {
    unsigned short ua = __builtin_bit_cast(unsigned short, (__bf16)a);
    unsigned short uc = __builtin_bit_cast(unsigned short, (__bf16)c);
    return ((unsigned)uc << 16) | ua;
}

__global__ __launch_bounds__(256, 4) void main_kernel(const float* __restrict__ X,
                                                      const float* __restrict__ J,
                                                      const __bf16* __restrict__ acat,
                                                      float* __restrict__ out) {
    __shared__ __align__(16) float lds[4096 + 4 * WLDS];  // 29,440 B

    const int tid  = threadIdx.x;
    const int wave = tid >> 6;
    const int lane = tid & 63;
    const int l15  = lane & 15;
    const int quad = lane >> 4;
    const int pbase = blockIdx.x * 16 + wave * 4;  // 4 points per wave

    // ---- per-lane direct J/X prefetch (issued first: longest latency) ----
    float2 jreg[4][3];
    float  xreg[4][3];
    {
        const float* Jb = J + (size_t)pbase * 384 + lane * 6;   // lane = d
        const float* Xb = X + (size_t)pbase * 192 + lane * 3;
        #pragma unroll
        for (int pi = 0; pi < 4; ++pi) {
            jreg[pi][0] = *(const float2*)(Jb + pi * 384);
            jreg[pi][1] = *(const float2*)(Jb + pi * 384 + 2);
            jreg[pi][2] = *(const float2*)(Jb + pi * 384 + 4);
            xreg[pi][0] = Xb[pi * 192];
            xreg[pi][1] = Xb[pi * 192 + 1];
            xreg[pi][2] = Xb[pi * 192 + 2];
        }
    }

    // ---- block-cooperative acat stage -> LDS, XOR-swizzled ----
    {
        const floatx4* ag = (const floatx4*)acat;  // 1024 float4
        floatx4 t[4];
        #pragma unroll
        for (int u = 0; u < 4; ++u) t[u] = ag[u * 256 + tid];
        #pragma unroll
        for (int u = 0; u < 4; ++u) {
            int Ld  = (u * 256 + tid) * 4;       // linear dword index
            int row = Ld >> 6;                   // acat row (f), 64 dwords/row
            int dst = Ld ^ ((row & 7) << 2);     // toggle dword bits 2..4
            *(floatx4*)(lds + dst) = t[u];
        }
    }
    __syncthreads();

    float* zbase = lds + 4096 + wave * WLDS;

    // ---- phase 1: pure-register geometry, lane = d ----
    #pragma unroll
    for (int pi = 0; pi < 4; ++pi) {
        float a0x = jreg[pi][0].x, a1x = jreg[pi][0].y;  // record [i][j] row-major
        float a0y = jreg[pi][1].x, a1y = jreg[pi][1].y;
        float a0z = jreg[pi][2].x, a1z = jreg[pi][2].y;
        float xx = xreg[pi][0], xy = xreg[pi][1], xz = xreg[pi][2];

        float n0 = sqrtf(a0x * a0x + a0y * a0y + a0z * a0z);
        float r0 = 1.0f / fmaxf(n0, 1e-12f);
        float b1x = a0x * r0, b1y = a0y * r0, b1z = a0z * r0;

        float d  = b1x * a1x + b1y * a1y + b1z * a1z;
        float ux = a1x - d * b1x, uy = a1y - d * b1y, uz = a1z - d * b1z;
        float n2 = sqrtf(ux * ux + uy * uy + uz * uz);
        float r2 = 1.0f / fmaxf(n2, 1e-12f);
        float b2x = ux * r2, b2y = uy * r2, b2z = uz * r2;

        float b3x = b1y * b2z - b1z * b2y;
        float b3y = b1z * b2x - b1x * b2z;
        float b3z = b1x * b2y - b1y * b2x;

        float rt0 = b1x * xx + b1y * xy + b1z * xz;
        float rt1 = b2x * xx + b2y * xy + b2z * xz;
        float rt2 = b3x * xx + b3y * xy + b3z * xz;

        float s = rt1 - rt2, tt = rt1 + rt2;

        unsigned* zr = (unsigned*)zbase + pi * (3 * ZRS);  // rows (pi, 0..2)
        zr[lane]           = pk(b2x * s + b3x * tt, b1x * rt0);
        zr[ZRS + lane]     = pk(b2y * s + b3y * tt, b1y * rt0);
        zr[2 * ZRS + lane] = pk(b2z * s + b3z * tt, b1z * rt0);
    }

    __asm__ volatile("s_waitcnt lgkmcnt(0)" ::: "memory");

    // ---- phase 2: 16x mfma 16x16x32, K=128, rows 0..11 valid ----
    floatx4 acc[4];
    #pragma unroll
    for (int mt = 0; mt < 4; ++mt) acc[mt] = (floatx4){0.f, 0.f, 0.f, 0.f};

    int row = l15 > 11 ? 11 : l15;  // clamp: n>=12 columns are garbage, never stored
    int pz  = (row * 21846) >> 16;  // row / 3
    int iz  = row - pz * 3;
    const __bf16* zb = (const __bf16*)zbase + pz * (3 * ZRS * 2) + iz * (ZRS * 2);
    const int sw = (l15 & 7) << 2;  // afrag swizzle (row-dependent dword XOR)
    #pragma unroll
    for (int kc = 0; kc < 4; ++kc) {
        bf16x8 b = *(const bf16x8*)(zb + kc * 32 + quad * 8);
        #pragma unroll
        for (int mt = 0; mt < 4; ++mt) {
            int r   = mt * 16 + l15;
            int off = r * 64 + ((kc * 16 + quad * 4) ^ sw);  // dwords
            bf16x8 a = *(const bf16x8*)((const __bf16*)lds + off * 2);
            acc[mt] = __builtin_amdgcn_mfma_f32_16x16x32_bf16(a, b, acc[mt], 0, 0, 0);
        }
    }

    __asm__ volatile("s_waitcnt lgkmcnt(0)" ::: "memory");

    // ---- epilogue: D[f][n] -> LDS [p_local*196 + f*3 + i] (aliases Z region) ----
    float* dl = zbase;
    #pragma unroll
    for (int mt = 0; mt < 4; ++mt) {
        int n = l15;
        if (n < 12) {
            int pl = (n * 21846) >> 16;  // n / 3
            int i  = n - pl * 3;
            float* dst = dl + pl * 196 + i;
            #pragma unroll
            for (int r = 0; r < 4; ++r) {
                int f = mt * 16 + quad * 4 + r;
                dst[f * 3] = acc[mt][r];
            }
        }
    }

    __asm__ volatile("s_waitcnt lgkmcnt(0)" ::: "memory");

    // ---- coalesced store: 4 points x 48 float4 = 192 float4 ----
    floatx4* og = (floatx4*)(out + (size_t)pbase * 192);
    #pragma unroll
    for (int t = 0; t < 3; ++t) {
        int g  = t * 64 + lane;
        int pg = (g * 1366) >> 16;  // g / 48
        int o  = g - pg * 48;
        og[g] = *(const floatx4*)(dl + pg * 196 + o * 4);
    }
}

extern "C" void kernel_launch(void* const* d_in, const int* in_sizes, int n_in,
                              void* d_out, int out_size, void* d_ws, size_t ws_size,
                              hipStream_t stream) {
    const float* X  = (const float*)d_in[0];
    const float* J  = (const float*)d_in[1];
    const float* A  = (const float*)d_in[2];
    const float* Bm = (const float*)d_in[3];
    const float* C  = (const float*)d_in[4];
    float* out = (float*)d_out;
    __bf16* acat = (__bf16*)d_ws;  // 64x128 bf16 = 16 KB

    prep_kernel<<<64, 64, 0, stream>>>(A, Bm, C, acat);

    // 65536 points = 4096 blocks x 4 waves x 4 points
    main_kernel<<<4096, 256, 0, stream>>>(X, J, acat, out);
}